// Round 1
// baseline (182.308 us; speedup 1.0000x reference)
//
#include <hip/hip_runtime.h>
#include <math.h>

#define NB 32
#define NT 2048
#define NC 1024
#define NH 8
#define ND 128
#define TCH 8
#define SCALE_F 0.08838834764831845f  // 1/sqrt(128)

__device__ __forceinline__ float wredsum(float v) {
#pragma unroll
  for (int off = 32; off > 0; off >>= 1) v += __shfl_xor(v, off, 64);
  return v;
}
__device__ __forceinline__ float wredmax(float v) {
#pragma unroll
  for (int off = 32; off > 0; off >>= 1) v = fmaxf(v, __shfl_xor(v, off, 64));
  return v;
}

// q[i] = query_token . q_w[i,:] + q_b[i]   (one wave per output, 1024 waves)
__global__ __launch_bounds__(256) void k_q(const float* __restrict__ qt,
                                           const float* __restrict__ q_w,
                                           const float* __restrict__ q_b,
                                           float* __restrict__ q) {
  int gw = (blockIdx.x * 256 + threadIdx.x) >> 6;
  int lane = threadIdx.x & 63;
  if (gw >= NC) return;
  const float4* a4 = (const float4*)qt;
  const float4* w4 = (const float4*)(q_w + (size_t)gw * NC);
  float acc = 0.f;
#pragma unroll
  for (int j = 0; j < 4; ++j) {
    float4 a = a4[lane + 64 * j];
    float4 w = w4[lane + 64 * j];
    acc += a.x * w.x + a.y * w.y + a.z * w.z + a.w * w.w;
  }
  acc = wredsum(acc);
  if (lane == 0) q[gw] = acc + q_b[gw];
}

// wq[h*NC+c] = sum_d q[h*ND+d]*kv_w[(h*ND+d)*NC + c];  qkb[h] = q[h,:].kv_b[h,:]
__global__ __launch_bounds__(256) void k_wq(const float* __restrict__ q,
                                            const float* __restrict__ kv_w,
                                            const float* __restrict__ kv_b,
                                            float* __restrict__ wq,
                                            float* __restrict__ qkb) {
  int tid = blockIdx.x * 256 + threadIdx.x;
  if (tid < NH * NC) {
    int h = tid >> 10;
    int c = tid & (NC - 1);
    const float* qh = q + h * ND;
    const float* w = kv_w + (size_t)(h * ND) * NC + c;
    float acc = 0.f;
#pragma unroll 4
    for (int d = 0; d < ND; ++d) acc = fmaf(qh[d], w[(size_t)d * NC], acc);
    wq[tid] = acc;
  }
  if (tid < NH) {
    const float* qh = q + tid * ND;
    const float* bb = kv_b + tid * ND;
    float acc = 0.f;
    for (int d = 0; d < ND; ++d) acc = fmaf(qh[d], bb[d], acc);
    qkb[tid] = acc;
  }
}

// Pass 1 over x: S[b,h,t] = (x[b,t,:].wq[h,:] + qkb[h])*scale + bias[t], masked
__global__ __launch_bounds__(256) void k_scores(const float* __restrict__ x,
                                                const int* __restrict__ mask,
                                                const float* __restrict__ wq,
                                                const float* __restrict__ qkb,
                                                float* __restrict__ S) {
  __shared__ float4 wq4[NH * 256];
  __shared__ float qkb_s[NH];
  for (int i = threadIdx.x; i < NH * 256; i += 256) wq4[i] = ((const float4*)wq)[i];
  if (threadIdx.x < NH) qkb_s[threadIdx.x] = qkb[threadIdx.x];
  __syncthreads();
  int lane = threadIdx.x & 63;
  int gw = (blockIdx.x * 256 + threadIdx.x) >> 6;
  int nw = gridDim.x * 4;
  for (int row0 = gw * 2; row0 < NB * NT; row0 += nw * 2) {
    float4 xv[2][4];
#pragma unroll
    for (int r = 0; r < 2; ++r) {
      const float4* xr = (const float4*)(x + (size_t)(row0 + r) * NC);
#pragma unroll
      for (int j = 0; j < 4; ++j) xv[r][j] = xr[lane + 64 * j];
    }
    float acc[2][NH];
#pragma unroll
    for (int r = 0; r < 2; ++r)
#pragma unroll
      for (int h = 0; h < NH; ++h) acc[r][h] = 0.f;
#pragma unroll
    for (int h = 0; h < NH; ++h) {
#pragma unroll
      for (int j = 0; j < 4; ++j) {
        float4 w = wq4[h * 256 + lane + 64 * j];
#pragma unroll
        for (int r = 0; r < 2; ++r) {
          acc[r][h] = fmaf(xv[r][j].x, w.x, acc[r][h]);
          acc[r][h] = fmaf(xv[r][j].y, w.y, acc[r][h]);
          acc[r][h] = fmaf(xv[r][j].z, w.z, acc[r][h]);
          acc[r][h] = fmaf(xv[r][j].w, w.w, acc[r][h]);
        }
      }
    }
#pragma unroll
    for (int r = 0; r < 2; ++r) {
      int row = row0 + r;
      int b = row >> 11;
      int t = row & (NT - 1);
      float bias = 2.0f * expf((float)t * (-3.0f / 2048.0f));
      int mk = mask[row];
#pragma unroll
      for (int h = 0; h < NH; ++h) {
        float v = wredsum(acc[r][h]);
        if (lane == h) {
          float s = (v + qkb_s[h]) * SCALE_F + bias;
          if (mk == 0) s = -INFINITY;
          S[((size_t)(b * NH + h)) * NT + t] = s;
        }
      }
    }
  }
}

// softmax over T for each (b,h); block per (b,h), 256 threads x 8 elems
__global__ __launch_bounds__(256) void k_softmax(float* __restrict__ S) {
  float* s = S + (size_t)blockIdx.x * NT;
  int tid = threadIdx.x;
  float v[8];
  float mx = -INFINITY;
#pragma unroll
  for (int j = 0; j < 8; ++j) {
    v[j] = s[tid + 256 * j];
    mx = fmaxf(mx, v[j]);
  }
  __shared__ float rmax[4], rsum[4];
  mx = wredmax(mx);
  if ((tid & 63) == 0) rmax[tid >> 6] = mx;
  __syncthreads();
  mx = fmaxf(fmaxf(rmax[0], rmax[1]), fmaxf(rmax[2], rmax[3]));
  float sum = 0.f;
#pragma unroll
  for (int j = 0; j < 8; ++j) {
    v[j] = expf(v[j] - mx);
    sum += v[j];
  }
  sum = wredsum(sum);
  if ((tid & 63) == 0) rsum[tid >> 6] = sum;
  __syncthreads();
  sum = rsum[0] + rsum[1] + rsum[2] + rsum[3];
  float inv = 1.0f / sum;
#pragma unroll
  for (int j = 0; j < 8; ++j) s[tid + 256 * j] = v[j] * inv;
}

// attn_weights[b,t] = mean_h attn[b,h,t]
__global__ __launch_bounds__(256) void k_mean(const float* __restrict__ A,
                                              float* __restrict__ ow) {
  int idx = blockIdx.x * 256 + threadIdx.x;
  int b = idx >> 11;
  int t = idx & (NT - 1);
  float sacc = 0.f;
#pragma unroll
  for (int h = 0; h < NH; ++h) sacc += A[((size_t)(b * NH + h)) * NT + t];
  ow[idx] = sacc * 0.125f;
}

// Pass 2 over x: partial xa[b,h,c] = sum_{t in chunk} attn[b,h,t]*x[b,t,c]
__global__ __launch_bounds__(256) void k_xa(const float* __restrict__ x,
                                            const float* __restrict__ A,
                                            float* __restrict__ part) {
  int bi = blockIdx.x;  // b*(4*TCH) + cc*TCH + tc
  int b = bi >> 5;
  int cc = (bi >> 3) & 3;
  int tc = bi & 7;
  int tid = threadIdx.x;
  int c = cc * 256 + tid;
  __shared__ float a_s[NH * 256];
#pragma unroll
  for (int j = 0; j < 8; ++j) {
    int i = tid + 256 * j;
    int h = i >> 8;
    int tl = i & 255;
    a_s[i] = A[((size_t)(b * NH + h)) * NT + tc * 256 + tl];
  }
  __syncthreads();
  float acc[NH];
#pragma unroll
  for (int h = 0; h < NH; ++h) acc[h] = 0.f;
  const float* xp = x + ((size_t)(b * NT + tc * 256)) * NC + c;
  for (int tl = 0; tl < 256; ++tl) {
    float xval = xp[(size_t)tl * NC];
#pragma unroll
    for (int h = 0; h < NH; ++h) acc[h] = fmaf(a_s[h * 256 + tl], xval, acc[h]);
  }
#pragma unroll
  for (int h = 0; h < NH; ++h)
    part[(((size_t)tc * NB + b) * NH + h) * NC + c] = acc[h];
}

// reduce partials over t-chunks
__global__ __launch_bounds__(256) void k_xared(const float* __restrict__ part,
                                               float* __restrict__ xa) {
  int idx = blockIdx.x * 256 + threadIdx.x;  // (b*NH+h)*NC + c
  float sacc = 0.f;
#pragma unroll
  for (int tc = 0; tc < TCH; ++tc) sacc += part[(size_t)tc * (NB * NH * NC) + idx];
  xa[idx] = sacc;
}

// pooled2[b, h*128+d] = xa[b,h,:].kv_w[NC + h*128+d, :] + kv_b[NC + h*128+d]
__global__ __launch_bounds__(256) void k_pv(const float* __restrict__ xa,
                                            const float* __restrict__ kv_w,
                                            const float* __restrict__ kv_b,
                                            float* __restrict__ p2) {
  int gw = (blockIdx.x * 256 + threadIdx.x) >> 6;
  int lane = threadIdx.x & 63;
  if (gw >= NB * NC) return;
  int b = gw >> 10;
  int hd = gw & (NC - 1);
  int h = hd >> 7;
  const float4* a4 = (const float4*)(xa + ((size_t)(b * NH + h)) * NC);
  const float4* w4 = (const float4*)(kv_w + ((size_t)(NC + hd)) * NC);
  float acc = 0.f;
#pragma unroll
  for (int j = 0; j < 4; ++j) {
    float4 a = a4[lane + 64 * j];
    float4 w = w4[lane + 64 * j];
    acc += a.x * w.x + a.y * w.y + a.z * w.z + a.w * w.w;
  }
  acc = wredsum(acc);
  if (lane == 0) p2[(size_t)b * NC + hd] = acc + kv_b[NC + hd];
}

// out[b,i] = p2[b,:].proj_w[i,:] + proj_b[i]
__global__ __launch_bounds__(256) void k_proj(const float* __restrict__ p2,
                                              const float* __restrict__ proj_w,
                                              const float* __restrict__ proj_b,
                                              float* __restrict__ out) {
  int gw = (blockIdx.x * 256 + threadIdx.x) >> 6;
  int lane = threadIdx.x & 63;
  if (gw >= NB * NC) return;
  int b = gw >> 10;
  int i = gw & (NC - 1);
  const float4* a4 = (const float4*)(p2 + (size_t)b * NC);
  const float4* w4 = (const float4*)(proj_w + (size_t)i * NC);
  float acc = 0.f;
#pragma unroll
  for (int j = 0; j < 4; ++j) {
    float4 a = a4[lane + 64 * j];
    float4 w = w4[lane + 64 * j];
    acc += a.x * w.x + a.y * w.y + a.z * w.z + a.w * w.w;
  }
  acc = wredsum(acc);
  if (lane == 0) out[(size_t)b * NC + i] = acc + proj_b[i];
}

extern "C" void kernel_launch(void* const* d_in, const int* in_sizes, int n_in,
                              void* d_out, int out_size, void* d_ws, size_t ws_size,
                              hipStream_t stream) {
  const float* x = (const float*)d_in[0];
  const int* mask = (const int*)d_in[1];
  const float* qt = (const float*)d_in[2];
  const float* kv_w = (const float*)d_in[3];
  const float* kv_b = (const float*)d_in[4];
  const float* q_w = (const float*)d_in[5];
  const float* q_b = (const float*)d_in[6];
  const float* proj_w = (const float*)d_in[7];
  const float* proj_b = (const float*)d_in[8];
  float* out = (float*)d_out;

  float* ws = (float*)d_ws;
  float* q = ws;                   // 1024
  float* wq = ws + 1024;           // 8192
  float* qkb = ws + 9216;          // 8 (padded to 512)
  float* S = ws + 9728;            // NB*NH*NT = 524288
  float* part = ws + 534528;       // TCH*NB*NH*NC = 2097152
  float* xa = ws + 2631680;        // NB*NH*NC = 262144
  float* p2 = ws + 2893824;        // NB*NC = 32768   (total ~11.2 MiB)

  k_q<<<256, 256, 0, stream>>>(qt, q_w, q_b, q);
  k_wq<<<32, 256, 0, stream>>>(q, kv_w, kv_b, wq, qkb);
  k_scores<<<2048, 256, 0, stream>>>(x, mask, wq, qkb, S);
  k_softmax<<<NB * NH, 256, 0, stream>>>(S);
  k_mean<<<NB * NT / 256, 256, 0, stream>>>(S, out + NB * NC);
  k_xa<<<NB * 4 * TCH, 256, 0, stream>>>(x, S, part);
  k_xared<<<NB * NH * NC / 256, 256, 0, stream>>>(part, xa);
  k_pv<<<(NB * NC) / 4, 256, 0, stream>>>(xa, kv_w, kv_b, p2);
  k_proj<<<(NB * NC) / 4, 256, 0, stream>>>(p2, proj_w, proj_b, out);
}